// Round 13
// baseline (152.278 us; speedup 1.0000x reference)
//
#include <hip/hip_runtime.h>
#include <hip/hip_fp16.h>
#include <hip/hip_bf16.h>

// Logic-gate network: 23 layers, widths [128]*16 + [64,32,16,8,4,2,1].
// Node j: out = c0 + c1*a + c2*b + c3*a*b; c = softmax(W[j]) @ GATE_COEFFS.
// N_CELLS = 262144 cells.
//
// R13: R12's 2-layer-fused structure + EXPLICIT SOFTWARE PIPELINING.
// R12 lesson: DS bytes x0.82 bought nothing; VGPR=28 meant the compiler
// alternated {4 ds_read -> full lgkmcnt stall -> compute} per unit, exposing
// ~120cyc LDS latency 8x/step. R13 chunks 4 units: batch 4 desc s_loads
// (SGPRs) -> 16 ds_read_b64 issued back-to-back -> compute 4 units, giving
// progressive lgkmcnt(12/8/4/0) waits; stall once per chunk, hidden under
// the other units' compute. Operand regs 32 + res 16 ~= 56 VGPR <= 64 so
// 2 blocks/CU x 16 waves = 32 waves/CU is preserved.
// fp16 storage+math (absmax 1.95e-3, thr 9.26e-3). 1024 thr.

#define N_CELLS     262144
#define TOTAL_NODES 2175
#define TOTAL_FUSED 1067       // 8*128 main + 32 + 8 + 2 + 1
#define CELLS       256        // cells per block (64 lanes x 4 packed fp16)
#define BLOCK       1024       // 16 waves
#define ROWS        128        // max layer width

__device__ const int LAYER_OFF[24] = {
    0, 128, 256, 384, 512, 640, 768, 896, 1024, 1152, 1280, 1408,
    1536, 1664, 1792, 1920, 2048, 2112, 2144, 2160, 2168, 2172, 2174, 2175
};

__device__ const float GC[16][4] = {
    {0, 0, 0, 0}, {0, 0, 0, 1}, {0, 1, 0, -1}, {0, 1, 0, 0},
    {0, 0, 1, -1}, {0, 0, 1, 0}, {0, 1, 1, -2}, {0, 1, 1, -1},
    {1, -1, -1, 1}, {1, -1, -1, 2}, {1, 0, -1, 0}, {1, 0, -1, 1},
    {1, -1, 0, 0}, {1, -1, 0, 1}, {1, 0, 0, -1}, {1, 0, 0, 0}
};

__device__ __forceinline__ unsigned int h2u(__half2 h) {
    return *reinterpret_cast<unsigned int*>(&h);
}
__device__ __forceinline__ __half2 u2h2(unsigned int u) {
    return *reinterpret_cast<__half2*>(&u);
}

// softmax(W[node]) @ GC -> 4 floats
__device__ __forceinline__ void softgc(const float* __restrict__ w, float* c) {
    float v[16];
    float m = -1e30f;
    #pragma unroll
    for (int i = 0; i < 16; ++i) { v[i] = w[i]; m = fmaxf(m, v[i]); }
    float s = 0.f;
    #pragma unroll
    for (int i = 0; i < 16; ++i) { v[i] = expf(v[i] - m); s += v[i]; }
    float inv = 1.0f / s;
    c[0] = c[1] = c[2] = c[3] = 0.f;
    #pragma unroll
    for (int i = 0; i < 16; ++i) {
        float p = v[i] * inv;
        c[0] += p * GC[i][0];
        c[1] += p * GC[i][1];
        c[2] += p * GC[i][2];
        c[3] += p * GC[i][3];
    }
}

__device__ __forceinline__ uint4 packc(const float* c) {
    uint4 r;
    r.x = h2u(__half2half2(__float2half(c[0])));
    r.y = h2u(__half2half2(__float2half(c[1])));
    r.z = h2u(__half2half2(__float2half(c[2])));
    r.w = h2u(__half2half2(__float2half(c[3])));
    return r;
}

// ---- Kernel A: build fused descriptors (64B each):
//   [0]=cA, [1]=cB, [2]=cO (half2-dup x4), [3]={iaA, ibA, iaB, ibB} rows.
__global__ void coeff_kernel(const float* __restrict__ W,
                             const int* __restrict__ idx_a,
                             const int* __restrict__ idx_b,
                             uint4* __restrict__ fdesc) {
    int f = blockIdx.x * blockDim.x + threadIdx.x;
    if (f >= TOTAL_FUSED) return;

    int L1, n;
    bool ident = false;
    if (f < 1024)      { int p = f >> 7; L1 = 2 * p + 1; n = f & 127; }
    else if (f < 1056) { L1 = 17; n = f - 1024; }
    else if (f < 1064) { L1 = 19; n = f - 1056; }
    else if (f < 1066) { L1 = 21; n = f - 1064; }
    else               { L1 = 22; n = 0; ident = true; }

    int g1 = LAYER_OFF[L1] + n;
    float cO[4], cA[4], cB[4];
    softgc(W + 16 * g1, cO);
    uint4 idx;
    if (!ident) {
        int L0 = L1 - 1;
        int gA = LAYER_OFF[L0] + idx_a[g1];
        int gB = LAYER_OFF[L0] + idx_b[g1];
        softgc(W + 16 * gA, cA);
        softgc(W + 16 * gB, cB);
        idx.x = idx_a[gA]; idx.y = idx_b[gA];
        idx.z = idx_a[gB]; idx.w = idx_b[gB];
    } else {
        // layer 22 solo: A = rowA, B = rowB via identity gates, out = gate(A,B)
        cA[0] = 0.f; cA[1] = 1.f; cA[2] = 0.f; cA[3] = 0.f;
        cB[0] = 0.f; cB[1] = 1.f; cB[2] = 0.f; cB[3] = 0.f;
        idx.x = idx.y = idx_a[g1];
        idx.z = idx.w = idx_b[g1];
    }
    fdesc[f * 4 + 0] = packc(cA);
    fdesc[f * 4 + 1] = packc(cB);
    fdesc[f * 4 + 2] = packc(cO);
    fdesc[f * 4 + 3] = idx;
}

// gate(a,b) = a*(c1 + c3*b) + (c0 + c2*b), packed fp16
__device__ __forceinline__ __half2 gate2(__half2 a, __half2 b, uint4 c) {
    return __hfma2(a, __hfma2(u2h2(c.w), b, u2h2(c.y)),
                      __hfma2(u2h2(c.z), b, u2h2(c.x)));
}

// One FUSED step (2 layers): wave q computes fused units [q*PER, q*PER+PER),
// software-pipelined in chunks of CH=4: batch desc s_loads -> batch 4*CH
// ds_read_b64 -> compute CH units (progressive lgkmcnt waits).
template<int PER>
__device__ __forceinline__ void fused_step(const uint4* __restrict__ fdesc,
                                           int off, int w,
                                           uint2 (* __restrict__ buf)[64],
                                           int q, int lane) {
    const int n0 = q * PER;
    uint2 res[PER];
    const bool active = (n0 < w);

    if (active) {
        constexpr int CH = (PER >= 4) ? 4 : PER;
        #pragma unroll
        for (int c0 = 0; c0 < PER; c0 += CH) {
            uint4 cA[CH], cB[CH], cO[CH], id[CH];
            uint2 vaA[CH], vbA[CH], vaB[CH], vbB[CH];
            // 1) batched wave-uniform descriptor loads (SGPRs)
            #pragma unroll
            for (int u = 0; u < CH; ++u) {
                int nu = __builtin_amdgcn_readfirstlane(n0 + c0 + u);
                const uint4* fd = fdesc + 4 * (off + nu);
                cA[u] = fd[0]; cB[u] = fd[1]; cO[u] = fd[2]; id[u] = fd[3];
            }
            // 2) batched operand reads: 4*CH ds_read_b64 back-to-back
            #pragma unroll
            for (int u = 0; u < CH; ++u) {
                vaA[u] = buf[id[u].x][lane];
                vbA[u] = buf[id[u].y][lane];
                vaB[u] = buf[id[u].z][lane];
                vbB[u] = buf[id[u].w][lane];
            }
            // 3) compute (unit u waits only its own reads: lgkmcnt(12/8/4/0))
            #pragma unroll
            for (int u = 0; u < CH; ++u) {
                __half2 A0 = gate2(u2h2(vaA[u].x), u2h2(vbA[u].x), cA[u]);
                __half2 A1 = gate2(u2h2(vaA[u].y), u2h2(vbA[u].y), cA[u]);
                __half2 B0 = gate2(u2h2(vaB[u].x), u2h2(vbB[u].x), cB[u]);
                __half2 B1 = gate2(u2h2(vaB[u].y), u2h2(vbB[u].y), cB[u]);
                res[c0 + u].x = h2u(gate2(A0, B0, cO[u]));
                res[c0 + u].y = h2u(gate2(A1, B1, cO[u]));
            }
        }
    }
    __syncthreads();                              // all reads done
    if (active) {
        #pragma unroll
        for (int j = 0; j < PER; ++j) {
            int nu = __builtin_amdgcn_readfirstlane(n0 + j);
            buf[nu][lane] = res[j];               // ds_write_b64
        }
    }
    __syncthreads();                              // all writes done
}

// ---- Kernel B: the network. 256 cells/block; single 64KB LDS buffer. ----
__global__ __launch_bounds__(BLOCK, 4)
void net_kernel(const float* __restrict__ x,
                const uint4* __restrict__ fdesc,
                float* __restrict__ out) {
    // 128 rows * 64 lanes * 8B = 64 KB -> 2 blocks/CU (32 waves/CU if VGPR<=64).
    __shared__ uint2 buf[ROWS][64];

    const int t    = threadIdx.x;
    const int lane = t & 63;        // cells lane, lane+64, lane+128, lane+192
    const int q    = t >> 6;        // wave id 0..15
    const size_t base = (size_t)blockIdx.x * CELLS;

    // Stage x (256 cells x 16 f32 = 16 KB) -> packed fp16 buf[k][lane][4].
    {
        const float4* xv = reinterpret_cast<const float4*>(x + base * 16);
        __half* hp = reinterpret_cast<__half*>(&buf[0][0]);
        float4 v = xv[t];                 // coalesced: 1024 float4
        int c  = t >> 2;                  // cell 0..255
        int k  = (t & 3) << 2;            // feature base
        int h  = c >> 6;                  // sub-slot 0..3
        int cl = c & 63;
        hp[((k + 0) * 64 + cl) * 4 + h] = __float2half(v.x);
        hp[((k + 1) * 64 + cl) * 4 + h] = __float2half(v.y);
        hp[((k + 2) * 64 + cl) * 4 + h] = __float2half(v.z);
        hp[((k + 3) * 64 + cl) * 4 + h] = __float2half(v.w);
    }
    __syncthreads();

    // Main fused pairs (0,1)..(14,15): 128 units each, PER=8 (16 waves).
    #pragma unroll 1
    for (int p = 0; p < 8; ++p)
        fused_step<8>(fdesc, p * 128, 128, buf, q, lane);
    // Tail fused pairs: (16,17)=32 units, (18,19)=8, (20,21)=2, layer22=1.
    fused_step<2>(fdesc, 1024, 32, buf, q, lane);
    fused_step<1>(fdesc, 1056,  8, buf, q, lane);
    fused_step<1>(fdesc, 1064,  2, buf, q, lane);
    fused_step<1>(fdesc, 1066,  1, buf, q, lane);

    // Final layer width 1: row 0, 4 packed cells per lane.
    if (t < CELLS) {
        int cl = t & 63, h = t >> 6;
        uint2 p = buf[0][cl];                 // broadcast read
        unsigned int u = (h < 2) ? p.x : p.y;
        __half2 hh = u2h2(u);
        out[base + t] = (h & 1) ? __high2float(hh) : __low2float(hh);
    }
}

extern "C" void kernel_launch(void* const* d_in, const int* in_sizes, int n_in,
                              void* d_out, int out_size, void* d_ws, size_t ws_size,
                              hipStream_t stream) {
    const float* x  = (const float*)d_in[0];
    const float* W  = (const float*)d_in[1];
    const int*   ia = (const int*)d_in[2];
    const int*   ib = (const int*)d_in[3];
    uint4* fdesc    = (uint4*)d_ws;   // 1067 * 64 B = 68.3 KB scratch

    coeff_kernel<<<(TOTAL_FUSED + 255) / 256, 256, 0, stream>>>(W, ia, ib, fdesc);

    const int grid = N_CELLS / CELLS;    // 1024 blocks
    net_kernel<<<grid, BLOCK, 0, stream>>>(x, fdesc, (float*)d_out);
}